// Round 5
// baseline (102.742 us; speedup 1.0000x reference)
//
#include <hip/hip_runtime.h>
#include <hip/hip_bf16.h>

#define NUM_MOLECULES 262144
#define NUM_ATOMS     8388608
#define TABLE_SIZE    100
#define BLOCK         256
#define CPT           8                   // atoms per thread: two int4 of z + two of m
#define TILE          (BLOCK * CPT)       // 2048 atoms per block
#define SLOTS         TILE                // LDS accumulator slots (span fallback if exceeded)

// Kernel 1: out[m] = energy_readout[m]  (d_out is poisoned 0xAA before every call).
// Still required: covers molecules with zero atoms / gaps between tile spans.
__global__ void init_out_kernel(const float* __restrict__ energy,
                                float* __restrict__ out, int n4) {
    int i = blockIdx.x * blockDim.x + threadIdx.x;
    if (i < n4) {
        reinterpret_cast<float4*>(out)[i] =
            reinterpret_cast<const float4*>(energy)[i];
    }
}

// Kernel 2: block-private segmented sum.
// Sorted indices => molecules strictly inside a tile's [first,last] span are
// wholly owned by this block: accumulate runs into LDS (fast per-CU atomics),
// then non-atomic coalesced writes out[m]=energy[m]+sum for the interior and
// just TWO global atomics per block (first & last molecule).
__global__ void __launch_bounds__(BLOCK)
accum_kernel(const int* __restrict__ atomic_numbers,
             const int* __restrict__ mol_idx,
             const float* __restrict__ table,
             const float* __restrict__ energy,
             float* __restrict__ out) {
    __shared__ float tab[TABLE_SIZE];
    __shared__ float sums[SLOTS];
    __shared__ int s_first, s_last;

    const int tidx = threadIdx.x;
    if (tidx < TABLE_SIZE) tab[tidx] = table[tidx];
#pragma unroll
    for (int k = 0; k < SLOTS / BLOCK; ++k)
        sums[k * BLOCK + tidx] = 0.0f;

    const int gtid = blockIdx.x * BLOCK + tidx;
    const int4* zp = reinterpret_cast<const int4*>(atomic_numbers);
    const int4* mp = reinterpret_cast<const int4*>(mol_idx);
    const int4 zzA = zp[2 * gtid], zzB = zp[2 * gtid + 1];
    const int4 mmA = mp[2 * gtid], mmB = mp[2 * gtid + 1];

    if (tidx == 0)         s_first = mmA.x;
    if (tidx == BLOCK - 1) s_last  = mmB.w;
    __syncthreads();
    const int first = s_first;
    const int last  = s_last;
    const int span1 = last - first + 1;   // #slots needed (>=1)

    const int   m_all[8] = {mmA.x, mmA.y, mmA.z, mmA.w, mmB.x, mmB.y, mmB.z, mmB.w};
    const float v_all[8] = {tab[zzA.x], tab[zzA.y], tab[zzA.z], tab[zzA.w],
                            tab[zzB.x], tab[zzB.y], tab[zzB.z], tab[zzB.w]};

    if (span1 <= SLOTS) {
        // ---- fast path: run-length parse -> LDS atomic per run ----
        int   curm = m_all[0];
        float run  = v_all[0];
#pragma unroll
        for (int j = 1; j < CPT; ++j) {
            if (m_all[j] == curm) {
                run += v_all[j];
            } else {
                atomicAdd(&sums[curm - first], run);
                curm = m_all[j];
                run  = v_all[j];
            }
        }
        atomicAdd(&sums[curm - first], run);
        __syncthreads();

        // interior molecules (strictly between first and last): exclusive owner
        for (int i = tidx + 1; i < span1 - 1; i += BLOCK)
            out[first + i] = energy[first + i] + sums[i];
        // boundary molecules may be shared with neighboring tiles
        if (tidx == 0) atomicAdd(out + first, sums[0]);
        if (tidx == 1 && last > first) atomicAdd(out + last, sums[span1 - 1]);
    } else {
        // ---- fallback (adversarial gaps): per-run global atomics ----
        int   curm = m_all[0];
        float run  = v_all[0];
#pragma unroll
        for (int j = 1; j < CPT; ++j) {
            if (m_all[j] == curm) {
                run += v_all[j];
            } else {
                atomicAdd(out + curm, run);
                curm = m_all[j];
                run  = v_all[j];
            }
        }
        atomicAdd(out + curm, run);
    }
}

extern "C" void kernel_launch(void* const* d_in, const int* in_sizes, int n_in,
                              void* d_out, int out_size, void* d_ws, size_t ws_size,
                              hipStream_t stream) {
    const float* energy_readout = (const float*)d_in[0];
    const int*   atomic_numbers = (const int*)d_in[1];
    const int*   mol_idx        = (const int*)d_in[2];
    const float* table          = (const float*)d_in[3];
    float* out = (float*)d_out;

    // Kernel 1: copy energy_readout -> out (float4)
    int n4 = NUM_MOLECULES / 4;                 // 65536
    int b1 = 256;
    int g1 = (n4 + b1 - 1) / b1;                // 256 blocks
    init_out_kernel<<<g1, b1, 0, stream>>>(energy_readout, out, n4);

    // Kernel 2: block-aggregated segmented accumulation, 4096 blocks
    int g2 = NUM_ATOMS / TILE;                  // 4096
    accum_kernel<<<g2, BLOCK, 0, stream>>>(atomic_numbers, mol_idx, table,
                                           energy_readout, out);
}

// Round 6
// 98.965 us; speedup vs baseline: 1.0382x; 1.0382x over previous
//
#include <hip/hip_runtime.h>
#include <hip/hip_bf16.h>

#define NUM_MOLECULES 262144
#define NUM_ATOMS     8388608
#define TABLE_SIZE    100
#define BLOCK         256
#define CPT           8                   // atoms per thread: two int4 of z + two of m

// Kernel 1: out[m] = energy_readout[m]  (d_out is poisoned 0xAA before every call)
__global__ void init_out_kernel(const float* __restrict__ energy,
                                float* __restrict__ out, int n4) {
    int i = blockIdx.x * blockDim.x + threadIdx.x;
    if (i < n4) {
        reinterpret_cast<float4*>(out)[i] =
            reinterpret_cast<const float4*>(energy)[i];
    }
}

// Kernel 2: per-thread parse of 8 sorted atoms + wave-level head-flagged
// segmented scan (Hillis-Steele over 64 lanes) -> ~1 atomicAdd per segment run.
// No data LDS, no __syncthreads in the hot path, fully coalesced int4 loads.
// Measured best variant (R4: 100.0 us total, accum ~16 us vs ~13.5 us floor).
__global__ void __launch_bounds__(BLOCK)
accum_kernel(const int* __restrict__ atomic_numbers,
             const int* __restrict__ mol_idx,
             const float* __restrict__ table,
             float* __restrict__ out) {
    __shared__ float tab[TABLE_SIZE];
    if (threadIdx.x < TABLE_SIZE) tab[threadIdx.x] = table[threadIdx.x];
    __syncthreads();

    const int tid = blockIdx.x * blockDim.x + threadIdx.x;
    const int4* zp = reinterpret_cast<const int4*>(atomic_numbers);
    const int4* mp = reinterpret_cast<const int4*>(mol_idx);
    const int4 zzA = zp[2 * tid], zzB = zp[2 * tid + 1];
    const int4 mmA = mp[2 * tid], mmB = mp[2 * tid + 1];

    const int m_all[8] = {mmA.x, mmA.y, mmA.z, mmA.w, mmB.x, mmB.y, mmB.z, mmB.w};
    const float v_all[8] = {tab[zzA.x], tab[zzA.y], tab[zzA.z], tab[zzA.w],
                            tab[zzB.x], tab[zzB.y], tab[zzB.z], tab[zzB.w]};

    // ---- local parse of 8 atoms into head run / interior runs / tail run ----
    int   curm = m_all[0];
    float run  = v_all[0];
    float head_sum = 0.0f;     // sum of leading run (valid iff nbound > 0)
    int   nbound = 0;          // number of molecule changes inside this thread
#pragma unroll
    for (int j = 1; j < CPT; ++j) {
        if (m_all[j] == curm) {
            run += v_all[j];
        } else {
            if (nbound == 0) head_sum = run;            // head run closes (may connect backward)
            else atomicAdd(out + curm, run);            // interior complete run
            ++nbound;
            curm = m_all[j];
            run  = v_all[j];
        }
    }
    const int   head_mol = m_all[0];
    const int   tail_mol = curm;       // == m_all[7]
    const float tail_sum = run;

    const int lane = threadIdx.x & 63;

    // ---- cross-lane connectivity ----
    const int prev_tail = __shfl_up(tail_mol, 1);
    const bool connect = (lane > 0) && (head_mol == prev_tail);
    // "open": incoming run flows through this whole lane into its tail
    const bool open = (nbound == 0) && connect;

    // ---- segmented inclusive scan of tail_sum, head flag = !open ----
    float c = tail_sum;
    int   f = open ? 0 : 1;
#pragma unroll
    for (int d = 1; d < 64; d <<= 1) {
        float cp = __shfl_up(c, d);
        int   fp = __shfl_up(f, d);
        if (lane >= d && !f) {
            c += cp;
            f |= fp;
        }
    }
    // c = sum of the open tail-run chain ending at this lane

    // ---- flush the incoming head run (boundary lanes close it) ----
    const float cin = __shfl_up(c, 1);   // chain total through lane-1 (valid iff connect)
    if (nbound > 0) {
        atomicAdd(out + head_mol, head_sum + (connect ? cin : 0.0f));
    }

    // ---- flush tail chains not absorbed by the next lane ----
    const int next_connect = __shfl_down((int)connect, 1);
    const bool chain_end = (lane == 63) || !next_connect;
    if (chain_end) {
        atomicAdd(out + tail_mol, c);
    }
}

extern "C" void kernel_launch(void* const* d_in, const int* in_sizes, int n_in,
                              void* d_out, int out_size, void* d_ws, size_t ws_size,
                              hipStream_t stream) {
    const float* energy_readout = (const float*)d_in[0];
    const int*   atomic_numbers = (const int*)d_in[1];
    const int*   mol_idx        = (const int*)d_in[2];
    const float* table          = (const float*)d_in[3];
    float* out = (float*)d_out;

    // Kernel 1: copy energy_readout -> out (float4)
    int n4 = NUM_MOLECULES / 4;                 // 65536
    int b1 = 256;
    int g1 = (n4 + b1 - 1) / b1;                // 256 blocks
    init_out_kernel<<<g1, b1, 0, stream>>>(energy_readout, out, n4);

    // Kernel 2: segmented accumulation, 4096 blocks x 256 threads, 8 atoms/thread
    int g2 = NUM_ATOMS / (BLOCK * CPT);         // 4096
    accum_kernel<<<g2, BLOCK, 0, stream>>>(atomic_numbers, mol_idx, table, out);
}